// Round 1
// 10501.001 us; speedup vs baseline: 2.5342x; 2.5342x over previous
//
#include <hip/hip_runtime.h>
#include <math.h>

// Problem constants
#define B_ 32
#define T_ 12
#define N_ 1024
#define D_ 64
#define L_ 2

constexpr int ND  = N_ * D_;        // 65536
constexpr int BND = B_ * N_ * D_;   // 2097152
constexpr long long NN = (long long)N_ * N_; // 1048576

// ---------------------------------------------------------------------------
// QK kernel: out[1024,64] = z[1024,64] @ W[64,64], per (b, which).
// Register-tiled: block = 128 rows x 64 cols, thread tile 8x4 (tx 16 x ty 16).
// Z tile in LDS XOR-swizzled [r][16 chunks]; W k-transposed [k>>2][n][k&3].
// ---------------------------------------------------------------------------
__global__ __launch_bounds__(256) void qk_kernel(
    const float* __restrict__ zx, int zx_sb,
    const float* __restrict__ zh, int zh_sb,
    const float* __restrict__ Wqx, const float* __restrict__ Wkx,
    const float* __restrict__ Wqh, const float* __restrict__ Wkh,
    float* __restrict__ qx, float* __restrict__ kx,
    float* __restrict__ qh, float* __restrict__ kh)
{
    int i0 = blockIdx.x * 128;
    int b  = blockIdx.y;
    int which = blockIdx.z;
    const float* z; const float* W; float* out;
    if (which == 0)      { z = zx + (size_t)b * zx_sb; W = Wqx; out = qx; }
    else if (which == 1) { z = zx + (size_t)b * zx_sb; W = Wkx; out = kx; }
    else if (which == 2) { z = zh + (size_t)b * zh_sb; W = Wqh; out = qh; }
    else                 { z = zh + (size_t)b * zh_sb; W = Wkh; out = kh; }
    out += (size_t)b * ND;

    __shared__ float4 Zs[128 * 16];   // [r][chunk^ (r&15)]
    __shared__ float  Ws[16][64][4];  // [k>>2][n][k&3]

    int tid = threadIdx.x;
    #pragma unroll
    for (int it = 0; it < 8; ++it) {
        int idx = tid + it * 256;
        int r = idx >> 4, c = idx & 15;
        Zs[r * 16 + (c ^ (r & 15))] =
            *(const float4*)(z + (size_t)(i0 + r) * 64 + c * 4);
    }
    #pragma unroll
    for (int it = 0; it < 4; ++it) {
        int idx = tid + it * 256;
        int kk = idx >> 4, n4 = (idx & 15) * 4;
        float4 v = *(const float4*)(W + (size_t)kk * 64 + n4);
        Ws[kk >> 2][n4 + 0][kk & 3] = v.x;
        Ws[kk >> 2][n4 + 1][kk & 3] = v.y;
        Ws[kk >> 2][n4 + 2][kk & 3] = v.z;
        Ws[kk >> 2][n4 + 3][kk & 3] = v.w;
    }
    __syncthreads();

    int tx = tid & 15, ty = tid >> 4;
    float acc[8][4];
    #pragma unroll
    for (int i = 0; i < 8; ++i)
        #pragma unroll
        for (int j = 0; j < 4; ++j) acc[i][j] = 0.f;

    #pragma unroll 2
    for (int s = 0; s < 16; ++s) {   // k4 = 4*s
        float4 af[8], wf[4];
        #pragma unroll
        for (int h = 0; h < 2; ++h)
            #pragma unroll
            for (int ii = 0; ii < 4; ++ii) {
                int m = h * 64 + ty * 4 + ii;
                af[h * 4 + ii] = Zs[m * 16 + (s ^ (m & 15))];
            }
        #pragma unroll
        for (int j = 0; j < 4; ++j)
            wf[j] = *(const float4*)&Ws[s][tx + 16 * j][0];
        #pragma unroll
        for (int i = 0; i < 8; ++i)
            #pragma unroll
            for (int j = 0; j < 4; ++j) {
                acc[i][j] += af[i].x * wf[j].x;
                acc[i][j] += af[i].y * wf[j].y;
                acc[i][j] += af[i].z * wf[j].z;
                acc[i][j] += af[i].w * wf[j].w;
            }
    }
    #pragma unroll
    for (int i = 0; i < 8; ++i) {
        int m = (i >> 2) * 64 + ty * 4 + (i & 3);
        #pragma unroll
        for (int j = 0; j < 4; ++j)
            out[(size_t)(i0 + m) * 64 + tx + 16 * j] = acc[i][j];
    }
}

// ---------------------------------------------------------------------------
// Scores kernel: S[i,j] = dot(q[i,:], k[j,:]) * 0.125.
// Block tile 128x128, K=64 full depth. Thread tile 8x8 (tx 16 x ty 16):
// rows m = 64h + 4ty + ii, cols n = tx + 16jj. Both tiles XOR-swizzled.
// ---------------------------------------------------------------------------
__global__ __launch_bounds__(256) void scores_kernel(
    const float* __restrict__ qx, const float* __restrict__ kx,
    const float* __restrict__ qh, const float* __restrict__ kh,
    float* __restrict__ ax, float* __restrict__ ah, int l)
{
    int i0 = blockIdx.x * 128, j0 = blockIdx.y * 128;
    int att = blockIdx.z & 1, b = blockIdx.z >> 1;
    const float* q = (att ? qh : qx) + (size_t)b * ND;
    const float* k = (att ? kh : kx) + (size_t)b * ND;
    float* S = (att ? ah : ax) + (size_t)(b * L_ + l) * NN;

    __shared__ float4 Qs[128 * 16];
    __shared__ float4 Ks[128 * 16];

    int tid = threadIdx.x;
    #pragma unroll
    for (int it = 0; it < 8; ++it) {
        int idx = tid + it * 256;
        int r = idx >> 4, c = idx & 15;
        int sw = c ^ (r & 15);
        Qs[r * 16 + sw] = *(const float4*)(q + (size_t)(i0 + r) * 64 + c * 4);
        Ks[r * 16 + sw] = *(const float4*)(k + (size_t)(j0 + r) * 64 + c * 4);
    }
    __syncthreads();

    int tx = tid & 15, ty = tid >> 4;
    float acc[8][8];
    #pragma unroll
    for (int i = 0; i < 8; ++i)
        #pragma unroll
        for (int j = 0; j < 8; ++j) acc[i][j] = 0.f;

    #pragma unroll 2
    for (int s = 0; s < 16; ++s) {
        float4 qf[8], kf[8];
        #pragma unroll
        for (int h = 0; h < 2; ++h)
            #pragma unroll
            for (int ii = 0; ii < 4; ++ii) {
                int m = h * 64 + ty * 4 + ii;
                qf[h * 4 + ii] = Qs[m * 16 + (s ^ (m & 15))];
            }
        #pragma unroll
        for (int j = 0; j < 8; ++j) {
            int n = tx + 16 * j;
            kf[j] = Ks[n * 16 + (s ^ (n & 15))];
        }
        #pragma unroll
        for (int i = 0; i < 8; ++i)
            #pragma unroll
            for (int j = 0; j < 8; ++j) {
                acc[i][j] += qf[i].x * kf[j].x;
                acc[i][j] += qf[i].y * kf[j].y;
                acc[i][j] += qf[i].z * kf[j].z;
                acc[i][j] += qf[i].w * kf[j].w;
            }
    }

    #pragma unroll
    for (int i = 0; i < 8; ++i) {
        int m = (i >> 2) * 64 + ty * 4 + (i & 3);
        float* Srow = S + (size_t)(i0 + m) * N_ + j0;
        #pragma unroll
        for (int j = 0; j < 8; ++j)
            Srow[tx + 16 * j] = acc[i][j] * 0.125f;
    }
}

// ---------------------------------------------------------------------------
// Softmax over rows of 1024, in place. One block (256 threads) per row.
// ---------------------------------------------------------------------------
__global__ __launch_bounds__(256) void softmax_kernel(
    float* __restrict__ ax, float* __restrict__ ah, int l)
{
    int i = blockIdx.x, b = blockIdx.y, att = blockIdx.z;
    float* row = (att ? ah : ax) + (size_t)(b * L_ + l) * NN + (size_t)i * N_;
    int tid = threadIdx.x;

    float4 v = ((const float4*)row)[tid];
    float m = fmaxf(fmaxf(v.x, v.y), fmaxf(v.z, v.w));
    #pragma unroll
    for (int off = 32; off; off >>= 1)
        m = fmaxf(m, __shfl_xor(m, off, 64));

    __shared__ float red_m[4], red_s[4];
    if ((tid & 63) == 0) red_m[tid >> 6] = m;
    __syncthreads();
    m = fmaxf(fmaxf(red_m[0], red_m[1]), fmaxf(red_m[2], red_m[3]));

    float e0 = __expf(v.x - m), e1 = __expf(v.y - m);
    float e2 = __expf(v.z - m), e3 = __expf(v.w - m);
    float s = e0 + e1 + e2 + e3;
    #pragma unroll
    for (int off = 32; off; off >>= 1)
        s += __shfl_xor(s, off, 64);
    if ((tid & 63) == 0) red_s[tid >> 6] = s;
    __syncthreads();
    s = red_s[0] + red_s[1] + red_s[2] + red_s[3];

    float inv = 1.f / s;
    ((float4*)row)[tid] = make_float4(e0 * inv, e1 * inv, e2 * inv, e3 * inv);
}

// ---------------------------------------------------------------------------
// AV kernel: g[i,:] = sum_j a[i,j] * z[j,:]  (M=1024, K=1024, N=64).
// Block tile 128 rows x 64 cols, K-chunks of 64. Thread tile 8x4.
// A tile XOR-swizzled [r][16 chunks]; Z tile k-transposed [k>>2][n][k&3].
// ---------------------------------------------------------------------------
__global__ __launch_bounds__(256) void av_kernel(
    const float* __restrict__ ax, const float* __restrict__ ah,
    const float* __restrict__ zx, int zx_sb,
    const float* __restrict__ zh, int zh_sb,
    float* __restrict__ gx, float* __restrict__ gh, int l)
{
    int i0 = blockIdx.x * 128;
    int att = blockIdx.y & 1, b = blockIdx.y >> 1;
    const float* a = (att ? ah : ax) + (size_t)(b * L_ + l) * NN;
    const float* z = att ? (zh + (size_t)b * zh_sb) : (zx + (size_t)b * zx_sb);
    float* out = (att ? gh : gx) + (size_t)b * ND;

    __shared__ float4 As[128 * 16];   // [r][chunk ^ (r&15)]
    __shared__ float  Zs[16][64][4];  // [k>>2][n][k&3] per 64-chunk

    int tid = threadIdx.x;
    int tx = tid & 15, ty = tid >> 4;
    float acc[8][4];
    #pragma unroll
    for (int i = 0; i < 8; ++i)
        #pragma unroll
        for (int j = 0; j < 4; ++j) acc[i][j] = 0.f;

    for (int kc = 0; kc < 16; ++kc) {
        __syncthreads();
        // A tile: 128 x 64
        #pragma unroll
        for (int it = 0; it < 8; ++it) {
            int idx = tid + it * 256;
            int r = idx >> 4, c = idx & 15;
            As[r * 16 + (c ^ (r & 15))] =
                *(const float4*)(a + (size_t)(i0 + r) * N_ + kc * 64 + c * 4);
        }
        // Z tile: 64 x 64, k-transposed
        #pragma unroll
        for (int it = 0; it < 4; ++it) {
            int idx = tid + it * 256;
            int kk = idx >> 4, n4 = (idx & 15) * 4;
            float4 v = *(const float4*)(z + (size_t)(kc * 64 + kk) * 64 + n4);
            Zs[kk >> 2][n4 + 0][kk & 3] = v.x;
            Zs[kk >> 2][n4 + 1][kk & 3] = v.y;
            Zs[kk >> 2][n4 + 2][kk & 3] = v.z;
            Zs[kk >> 2][n4 + 3][kk & 3] = v.w;
        }
        __syncthreads();

        #pragma unroll 2
        for (int s = 0; s < 16; ++s) {
            float4 af[8], zf[4];
            #pragma unroll
            for (int h = 0; h < 2; ++h)
                #pragma unroll
                for (int ii = 0; ii < 4; ++ii) {
                    int m = h * 64 + ty * 4 + ii;
                    af[h * 4 + ii] = As[m * 16 + (s ^ (m & 15))];
                }
            #pragma unroll
            for (int j = 0; j < 4; ++j)
                zf[j] = *(const float4*)&Zs[s][tx + 16 * j][0];
            #pragma unroll
            for (int i = 0; i < 8; ++i)
                #pragma unroll
                for (int j = 0; j < 4; ++j) {
                    acc[i][j] += af[i].x * zf[j].x;
                    acc[i][j] += af[i].y * zf[j].y;
                    acc[i][j] += af[i].z * zf[j].z;
                    acc[i][j] += af[i].w * zf[j].w;
                }
        }
    }

    #pragma unroll
    for (int i = 0; i < 8; ++i) {
        int m = (i >> 2) * 64 + ty * 4 + (i & 3);
        #pragma unroll
        for (int j = 0; j < 4; ++j)
            out[(size_t)(i0 + m) * 64 + tx + 16 * j] = acc[i][j];
    }
}

// ---------------------------------------------------------------------------
// Fused gates + GRU kernel (unchanged from previous round).
// ---------------------------------------------------------------------------
__global__ __launch_bounds__(256) void gru_kernel(
    const float* __restrict__ gx, const float* __restrict__ gh,
    const float* __restrict__ Wxl, const float* __restrict__ Whl,
    const float* __restrict__ bl,
    float* __restrict__ hid, float* __restrict__ y, int l, int t)
{
    int n0 = blockIdx.x * 32;
    int b  = blockIdx.y;
    const float* gxb = gx + (size_t)b * ND;
    const float* ghb = gh + (size_t)b * ND;

    __shared__ float Gx[32][65], Gh[32][65];
    int tid = threadIdx.x;
    #pragma unroll
    for (int i = 0; i < 8; ++i) {
        int idx = tid + i * 256;
        int r = idx >> 6, c = idx & 63;
        Gx[r][c] = gxb[(size_t)(n0 + r) * 64 + c];
        Gh[r][c] = ghb[(size_t)(n0 + r) * 64 + c];
    }
    __syncthreads();

    int d  = tid & 63;
    int rg = tid >> 6;  // 0..3, 8 rows each
    float iz[8] = {0}, ir[8] = {0}, in_[8] = {0};
    float hz[8] = {0}, hr[8] = {0}, hn[8] = {0};

    #pragma unroll 2
    for (int k = 0; k < 64; ++k) {
        float wx0 = Wxl[k * 192 + d];
        float wx1 = Wxl[k * 192 + 64 + d];
        float wx2 = Wxl[k * 192 + 128 + d];
        float wh0 = Whl[k * 192 + d];
        float wh1 = Whl[k * 192 + 64 + d];
        float wh2 = Whl[k * 192 + 128 + d];
        #pragma unroll
        for (int r = 0; r < 8; ++r) {
            float a = Gx[rg * 8 + r][k];
            float h = Gh[rg * 8 + r][k];
            iz[r] += a * wx0; ir[r] += a * wx1; in_[r] += a * wx2;
            hz[r] += h * wh0; hr[r] += h * wh1; hn[r] += h * wh2;
        }
    }

    float b0 = bl[d], b1 = bl[64 + d], b2 = bl[128 + d];
    #pragma unroll
    for (int r = 0; r < 8; ++r) {
        int row = n0 + rg * 8 + r;
        size_t hidx = ((size_t)(b * L_ + l) * N_ + row) * 64 + d;
        float ho = hid[hidx];
        float zg  = 1.f / (1.f + __expf(-(iz[r] + b0 + hz[r])));
        float rg_ = 1.f / (1.f + __expf(-(ir[r] + b1 + hr[r])));
        float ng  = tanhf(in_[r] + b2 + rg_ * hn[r]);
        float hnew = (1.f - zg) * ng + zg * ho;
        hid[hidx] = hnew;
        if (y) y[((size_t)(b * T_ + t) * N_ + row) * 64 + d] = hnew;
    }
}

// ---------------------------------------------------------------------------
extern "C" void kernel_launch(void* const* d_in, const int* in_sizes, int n_in,
                              void* d_out, int out_size, void* d_ws, size_t ws_size,
                              hipStream_t stream)
{
    const float* x    = (const float*)d_in[0];  // [B,T,N,D]
    const float* Wq_x = (const float*)d_in[1];  // [L,D,D]
    const float* Wk_x = (const float*)d_in[2];
    const float* Wq_h = (const float*)d_in[3];
    const float* Wk_h = (const float*)d_in[4];
    const float* Wx   = (const float*)d_in[5];  // [L,D,3D]
    const float* Wh   = (const float*)d_in[6];
    const float* bias = (const float*)d_in[7];  // [L,3D]

    float* outp = (float*)d_out;
    float* y   = outp;                                   // [B,T,N,D]
    float* hid = y + (size_t)B_ * T_ * N_ * D_;          // [B,L,N,D] (live state)
    float* ax  = hid + (size_t)B_ * L_ * N_ * D_;        // [B,L,N,N]
    float* ah  = ax + (size_t)B_ * L_ * NN;              // [B,L,N,N]

    float* ws = (float*)d_ws;  // needs 6 * 8 MB = 48 MB
    float* qx = ws;
    float* kx = qx + BND;
    float* qh = kx + BND;
    float* kh = qh + BND;
    float* gx = kh + BND;
    float* gh = gx + BND;

    // h0 = 0
    hipMemsetAsync(hid, 0, sizeof(float) * (size_t)B_ * L_ * N_ * D_, stream);

    for (int t = 0; t < T_; ++t) {
        for (int l = 0; l < L_; ++l) {
            const float* zx; int zx_sb;
            if (l == 0) { zx = x + (size_t)t * ND; zx_sb = T_ * ND; } // x[:,t]
            else        { zx = hid;                zx_sb = L_ * ND; } // hidden[:,0] (post layer-0 update)
            const float* zh = hid + (size_t)l * ND; int zh_sb = L_ * ND; // hidden[:,l] (pre-update)

            qk_kernel<<<dim3(8, B_, 4), 256, 0, stream>>>(
                zx, zx_sb, zh, zh_sb,
                Wq_x + l * 4096, Wk_x + l * 4096,
                Wq_h + l * 4096, Wk_h + l * 4096,
                qx, kx, qh, kh);

            scores_kernel<<<dim3(8, 8, 2 * B_), 256, 0, stream>>>(
                qx, kx, qh, kh, ax, ah, l);

            softmax_kernel<<<dim3(N_, B_, 2), 256, 0, stream>>>(ax, ah, l);

            av_kernel<<<dim3(8, 2 * B_), 256, 0, stream>>>(
                ax, ah, zx, zx_sb, zh, zh_sb, gx, gh, l);

            gru_kernel<<<dim3(32, B_), 256, 0, stream>>>(
                gx, gh, Wx + l * D_ * 192, Wh + l * D_ * 192, bias + l * 192,
                hid, (l == L_ - 1) ? y : nullptr, l, t);
        }
    }
}